// Round 1
// baseline (729.164 us; speedup 1.0000x reference)
//
#include <hip/hip_runtime.h>
#include <stdint.h>

#define B_ROWS 4096
#define D_DIM  1024
#define E_NUM  8
#define C_DIM  4096
#define LOSS_COEF 0.01f
#define EPS_COMBINE 2.220446049250313e-16f

typedef float  f32x4  __attribute__((ext_vector_type(4)));
typedef __bf16 bf16x8 __attribute__((ext_vector_type(8)));

// RNE float -> bf16 bits (values here are tame; no NaN handling needed)
static __device__ __forceinline__ unsigned short f2bf(float f) {
    unsigned int u = __float_as_uint(f);
    u += 0x7fffu + ((u >> 16) & 1u);
    return (unsigned short)(u >> 16);
}

// async global->LDS, 16B per lane; LDS dest = wave-uniform base + lane*16
static __device__ __forceinline__ void async16(const void* g, void* l) {
    __builtin_amdgcn_global_load_lds(
        (const __attribute__((address_space(1))) unsigned int*)g,
        (__attribute__((address_space(3))) unsigned int*)l, 16, 0, 0);
}

#define NT_BLOCKS ((C_DIM / 64) * (D_DIM / 64) * E_NUM) // 8192 transpose blocks

// Fused prep: blocks [0, NT_BLOCKS) transpose w_exp fp32 [8][1024][4096] ->
// wT bf16 [8][4096][1024] (k-contiguous); blocks [NT_BLOCKS, +1024) do the
// gating (logits, top-4 softmax, gates, stats atomics, xb emission). Gating
// has no dependency on the transpose, so its blocks hide in the tail.
__global__ __launch_bounds__(256) void prep_kernel(
    const float* __restrict__ x,
    const float* __restrict__ wg,
    const float* __restrict__ wexp,
    unsigned short* __restrict__ xb,
    unsigned short* __restrict__ wT,
    float* __restrict__ gates,
    float* __restrict__ stats)
{
    const int t = threadIdx.x;
    if ((int)blockIdx.x < NT_BLOCKS) {
        __shared__ float T[64][68];           // pad 68: conflict-free col reads
        __shared__ unsigned short W[64][72];  // pad 72: 16B-aligned, even banks
        const int bid = blockIdx.x;
        const int e  = bid >> 10;             // 64 c-tiles * 16 k-tiles
        const int k0 = ((bid >> 6) & 15) * 64;
        const int c0 = (bid & 63) * 64;
        const float* src = wexp + ((size_t)e * D_DIM + k0) * C_DIM + c0;
        #pragma unroll
        for (int i = 0; i < 4; ++i) {
            int kr = i * 16 + (t >> 4);
            int cg = (t & 15) * 4;
            *(float4*)&T[kr][cg] = *(const float4*)(src + (size_t)kr * C_DIM + cg);
        }
        __syncthreads();
        {
            const int c  = t & 63;
            const int kq = (t >> 6) * 16;
            unsigned short h[16];
            #pragma unroll
            for (int j = 0; j < 16; ++j) h[j] = f2bf(T[kq + j][c]);
            *(uint4*)&W[c][kq]     = ((const uint4*)h)[0];
            *(uint4*)&W[c][kq + 8] = ((const uint4*)h)[1];
        }
        __syncthreads();
        unsigned short* dstb = wT + (size_t)e * C_DIM * D_DIM;
        #pragma unroll
        for (int r = 0; r < 2; ++r) {
            int i  = r * 256 + t;
            int c3 = i >> 3;
            int k8 = (i & 7) * 8;
            *(uint4*)(dstb + (size_t)(c0 + c3) * D_DIM + k0 + k8) = *(const uint4*)&W[c3][k8];
        }
    } else {
        __shared__ float simp[E_NUM], sload[E_NUM];
        if (t < E_NUM) { simp[t] = 0.0f; sload[t] = 0.0f; }
        __syncthreads();
        const int lane = t & 63;
        const int wid  = t >> 6;
        const int row  = ((int)blockIdx.x - NT_BLOCKS) * 4 + wid;

        float acc[8] = {0.f,0.f,0.f,0.f,0.f,0.f,0.f,0.f};
        #pragma unroll
        for (int i = 0; i < 4; ++i) {
            int d = i * 256 + lane * 4;
            float4 xv = *(const float4*)(x + (size_t)row * D_DIM + d);
            unsigned short hh[4] = { f2bf(xv.x), f2bf(xv.y), f2bf(xv.z), f2bf(xv.w) };
            *(uint2*)(xb + (size_t)row * D_DIM + d) = *(const uint2*)hh;
            float xa[4] = { xv.x, xv.y, xv.z, xv.w };
            #pragma unroll
            for (int j = 0; j < 4; ++j) {
                const float4* wp = (const float4*)(wg + (size_t)(d + j) * 8);
                float4 w0 = wp[0], w1 = wp[1];
                acc[0] += xa[j] * w0.x; acc[1] += xa[j] * w0.y;
                acc[2] += xa[j] * w0.z; acc[3] += xa[j] * w0.w;
                acc[4] += xa[j] * w1.x; acc[5] += xa[j] * w1.y;
                acc[6] += xa[j] * w1.z; acc[7] += xa[j] * w1.w;
            }
        }
        #pragma unroll
        for (int off = 32; off > 0; off >>= 1)
            #pragma unroll
            for (int e = 0; e < 8; ++e)
                acc[e] += __shfl_xor(acc[e], off, 64);
        if (lane == 0) {
            float val[4]; int idx[4]; unsigned used = 0;
            #pragma unroll
            for (int j = 0; j < 4; ++j) {       // strict > : lowest index wins ties
                float best = -1e30f; int bi = 0;
                for (int ee = 0; ee < 8; ++ee)
                    if (!(used & (1u << ee)) && acc[ee] > best) { best = acc[ee]; bi = ee; }
                used |= 1u << bi; val[j] = best; idx[j] = bi;
            }
            float mx = val[0], sum = 0.f, gv[4];
            #pragma unroll
            for (int j = 0; j < 4; ++j) { gv[j] = __expf(val[j] - mx); sum += gv[j]; }
            float inv = 1.0f / sum;
            float gout[8] = {0.f,0.f,0.f,0.f,0.f,0.f,0.f,0.f};
            #pragma unroll
            for (int j = 0; j < 4; ++j) gout[idx[j]] = gv[j] * inv;
            #pragma unroll
            for (int e = 0; e < 8; ++e) gates[(size_t)row * 8 + e] = gout[e];
            #pragma unroll
            for (int j = 0; j < 4; ++j) {
                atomicAdd(&simp[idx[j]], gv[j] * inv);
                atomicAdd(&sload[idx[j]], 1.0f);
            }
        }
        __syncthreads();
        if (t < E_NUM) {
            atomicAdd(&stats[t],          simp[t]);
            atomicAdd(&stats[E_NUM + t],  sload[t]);
        }
    }
}

// Fused dense MoE. Tile 128 rows x 64 cols, 4 waves (2x2), each wave 64x32 x
// 2 experts per pass (4 passes). LDS layout is LINEAR per fragment: A stored
// as [16-row group][k-chunk][row] so every ds_read_b128 is base + lane*16
// (conflict-free, same pattern as the global_load_lds write side). Double-
// buffered: k-step t+1 is issued before the compute of step t, one barrier
// per step, so the pre-barrier vmcnt drain lands after the MFMA work.
__global__ __launch_bounds__(256, 3) void moe_main_kernel(
    const unsigned short* __restrict__ xb,   // bf16 bits [4096][1024]
    const unsigned short* __restrict__ wT,   // bf16 bits [8][4096][1024]
    const float* __restrict__ bexp,          // [8][4096]
    const float* __restrict__ gates,         // [4096][8]
    const float* __restrict__ stats,         // [16] (complete after prep)
    float* __restrict__ out)                 // [4096][4096] (+ loss at end)
{
    __shared__ unsigned short As[2][4096];   // dbuf: 8 groups x 4 chunks x 16 rows x 8
    __shared__ unsigned short Bs[2][4096];   // dbuf: 2 e x 4 col-groups x 4 chunks x 16 x 8
    __shared__ float gs[128 * 9];            // gates tile (pad 9)
    __shared__ float bs[8 * 64];             // bias tile

    const int tid  = threadIdx.x;
    const int lane = tid & 63;
    const int wid  = tid >> 6;     // 0..3
    const int wm   = wid >> 1;     // 2x2 wave grid: 64 rows x 32 cols each
    const int wn   = wid & 1;
    const int q    = lane >> 4;
    const int ln   = lane & 15;
    const int row0 = blockIdx.x * 128;
    const int col0 = blockIdx.y * 64;

    // loss (stats are final: prep kernel completed before this launch)
    if (blockIdx.x == 0 && blockIdx.y == 0 && tid == 0) {
        float mi = 0.f, ml = 0.f;
        for (int e = 0; e < 8; ++e) { mi += stats[e]; ml += stats[8 + e]; }
        mi *= 0.125f; ml *= 0.125f;
        float vi = 0.f, vl = 0.f;
        for (int e = 0; e < 8; ++e) {
            float a = stats[e] - mi;     vi += a * a;
            float b = stats[8 + e] - ml; vl += b * b;
        }
        vi *= (1.0f / 7.0f); vl *= (1.0f / 7.0f);
        out[(size_t)B_ROWS * C_DIM] =
            (vi / (mi * mi + 1e-10f) + vl / (ml * ml + 1e-10f)) * LOSS_COEF;
    }

    #pragma unroll
    for (int i = 0; i < 4; ++i) {
        int idx = i * 256 + tid;
        gs[(idx >> 3) * 9 + (idx & 7)] = gates[(size_t)row0 * 8 + idx];
    }
    {
        int e = tid >> 5, c = tid & 31;
        bs[e * 64 + c]      = bexp[(size_t)e * C_DIM + col0 + c];
        bs[e * 64 + c + 32] = bexp[(size_t)e * C_DIM + col0 + c + 32];
    }

    // Staging geometry: wave w, lane l stages row (w*16 + (l&15)), k-chunk
    // (l>>4) to LDS linear slot base + l*16 -> LDS holds [group][chunk][row].
    // 4 lanes {r,16+r,32+r,48+r} still read one contiguous 64B row segment,
    // so global coalescing is unchanged vs the row-linear order.
    const int sr = tid & 15;
    const int sq = (tid >> 4) & 3;
    const unsigned short* gA = xb + (size_t)(row0 + wid * 16 + sr) * D_DIM + sq * 8;
    const int be = wid >> 1;                          // expert within pair
    const unsigned short* gB = wT + (size_t)be * C_DIM * D_DIM
                             + (size_t)(col0 + (wid & 1) * 32 + sr) * D_DIM + sq * 8;

    char* const a0 = (char*)&As[0][0] + wid * 1024;            // group wid
    char* const b0 = (char*)&Bs[0][0] + be * 4096 + (wid & 1) * 2048;

    auto stage = [&](int buf, int eg, int ko) {
        const size_t bo = (size_t)buf * 8192;
        async16(gA + ko,              a0 + bo);           // A rows 0-63
        async16(gA + ko + 64 * D_DIM, a0 + bo + 4096);    // A rows 64-127
        const unsigned short* gbe = gB + (size_t)eg * 2 * C_DIM * D_DIM + ko;
        async16(gbe,                  b0 + bo);           // B col-group cg
        async16(gbe + 16 * D_DIM,     b0 + bo + 1024);    // B col-group cg+1
    };

    const f32x4 vzero = {0.f, 0.f, 0.f, 0.f};
    f32x4 comb[4][2];
    #pragma unroll
    for (int i = 0; i < 4; ++i)
        #pragma unroll
        for (int j = 0; j < 2; ++j) comb[i][j] = vzero;

    int buf = 0;
    stage(0, 0, 0);
    __syncthreads();

    for (int eg = 0; eg < 4; ++eg) {
        f32x4 acc[4][2][2];                  // [fm][fn][expert]
        #pragma unroll
        for (int i = 0; i < 4; ++i)
            #pragma unroll
            for (int j = 0; j < 2; ++j)
                #pragma unroll
                for (int e = 0; e < 2; ++e) acc[i][j][e] = vzero;

        for (int kt = 0; kt < 32; ++kt) {
            const int s = (eg << 5) | kt;
            if (s < 127) {                    // prefetch next k-step (crosses eg)
                const int s1 = s + 1;
                stage(buf ^ 1, s1 >> 5, (s1 & 31) << 5);
            }

            const unsigned short* pa = &As[buf][0];
            const unsigned short* pb = &Bs[buf][0];
            bf16x8 af[4], bfr[2][2];
            #pragma unroll
            for (int fm = 0; fm < 4; ++fm)    // linear: base + lane*16 bytes
                af[fm] = *(const bf16x8*)(pa + (wm * 4 + fm) * 512 + lane * 8);
            #pragma unroll
            for (int fn = 0; fn < 2; ++fn)
                #pragma unroll
                for (int e = 0; e < 2; ++e)
                    bfr[fn][e] = *(const bf16x8*)(pb + e * 2048 + (wn * 2 + fn) * 512 + lane * 8);

            #pragma unroll
            for (int fm = 0; fm < 4; ++fm)
                #pragma unroll
                for (int fn = 0; fn < 2; ++fn)
                    #pragma unroll
                    for (int e = 0; e < 2; ++e)
                        acc[fm][fn][e] = __builtin_amdgcn_mfma_f32_16x16x32_bf16(
                            af[fm], bfr[fn][e], acc[fm][fn][e], 0, 0, 0);

            __syncthreads();                  // drains prefetch (post-compute)
            buf ^= 1;
        }

        // epilogue: comb += gate * exp(acc + bias)   (C/D: col=ln, row=q*4+r)
        #pragma unroll
        for (int e = 0; e < 2; ++e) {
            int eG = eg * 2 + e;
            #pragma unroll
            for (int fn = 0; fn < 2; ++fn) {
                float bval = bs[eG * 64 + wn * 32 + fn * 16 + ln];
                #pragma unroll
                for (int fm = 0; fm < 4; ++fm)
                    #pragma unroll
                    for (int r = 0; r < 4; ++r) {
                        float g = gs[(wm * 64 + fm * 16 + q * 4 + r) * 9 + eG];
                        comb[fm][fn][r] += g * __expf(acc[fm][fn][e][r] + bval);
                    }
            }
        }
    }

    #pragma unroll
    for (int fm = 0; fm < 4; ++fm)
        #pragma unroll
        for (int fn = 0; fn < 2; ++fn)
            #pragma unroll
            for (int r = 0; r < 4; ++r) {
                int row = row0 + wm * 64 + fm * 16 + q * 4 + r;
                int col = col0 + wn * 32 + fn * 16 + ln;
                float c = comb[fm][fn][r];
                c = (c == 0.0f) ? EPS_COMBINE : c;
                out[(size_t)row * C_DIM + col] = __logf(c);
            }
}

extern "C" void kernel_launch(void* const* d_in, const int* in_sizes, int n_in,
                              void* d_out, int out_size, void* d_ws, size_t ws_size,
                              hipStream_t stream) {
    const float* x    = (const float*)d_in[0];
    const float* wg   = (const float*)d_in[1];
    const float* wexp = (const float*)d_in[2];
    const float* bexp = (const float*)d_in[3];
    // d_in[4] is k==4 (hard-coded in kernels)
    float* out = (float*)d_out;
    char*  ws  = (char*)d_ws;

    unsigned short* wT    = (unsigned short*)ws;               // 67108864 B
    unsigned short* xb    = (unsigned short*)(ws + 67108864);  // 8388608 B
    float*          gates = (float*)(ws + 75497472);           // 131072 B
    float*          stats = (float*)(ws + 75628544);           // 64 B

    hipMemsetAsync(stats, 0, 16 * sizeof(float), stream);
    prep_kernel<<<NT_BLOCKS + B_ROWS / 4, 256, 0, stream>>>(
        x, wg, wexp, xb, wT, gates, stats);

    dim3 grid(B_ROWS / 128, C_DIM / 64);
    moe_main_kernel<<<grid, 256, 0, stream>>>(xb, wT, bexp, gates, stats, out);
}